// Round 2
// baseline (109.165 us; speedup 1.0000x reference)
//
#include <hip/hip_runtime.h>
#include <stdint.h>

#define M_BOXES 8192
#define MIN_CONF_F 0.25f
#define MIN_IOU_F 0.45f
#define VCAP 1024
#define NT 1024

typedef unsigned long long u64;
typedef unsigned int u32;

__device__ inline float scalar_to_float(const int* p) {
    int v = p[0];
    if (v > 0 && v < (1 << 20)) return (float)v;   // plain int (int32 or low word of int64)
    return __int_as_float(v);                      // was actually float bits
}

// Kernel 1: gather + validity compaction. Writes ZEROS for boxes/conf/keep
// (only kept entries get real values, scattered by nms_kernel), class for all.
// Valid entries append {key, clipped box} to workspace.
__global__ __launch_bounds__(256) void gather_kernel(
    const float* __restrict__ boxes_raw, const float* __restrict__ scores,
    const int* __restrict__ indices, const int* __restrict__ p_out_h,
    const int* __restrict__ p_out_w, float* __restrict__ out,
    u64* __restrict__ vkeys, float4* __restrict__ vboxes,
    int* __restrict__ vcount)
{
    int i = blockIdx.x * blockDim.x + threadIdx.x;
    if (i >= M_BOXES) return;
    int cls = indices[3 * i + 1];
    int idx = indices[3 * i + 2];
    float conf = scores[cls * M_BOXES + idx];
    *reinterpret_cast<float4*>(out + 4 * i) = make_float4(0.f, 0.f, 0.f, 0.f);
    out[4 * M_BOXES + i] = 0.f;         // conf (kept entries overwritten later)
    out[5 * M_BOXES + i] = (float)cls;  // class_ids output (keep-independent)
    out[6 * M_BOXES + i] = 0.f;         // keep
    bool valid = (conf > MIN_CONF_F) &&
                 (cls == 2 || cls == 3 || cls == 5 || cls == 7);
    if (valid) {
        float4 b = *reinterpret_cast<const float4*>(boxes_raw + 4 * idx); // y1,x1,y2,x2
        float W = scalar_to_float(p_out_w);
        float H = scalar_to_float(p_out_h);
        float4 c;
        c.x = fminf(fmaxf(b.y, 0.f), W);
        c.y = fminf(fmaxf(b.x, 0.f), H);
        c.z = fminf(fmaxf(b.w, 0.f), W);
        c.w = fminf(fmaxf(b.z, 0.f), H);
        int p = atomicAdd(vcount, 1);
        if (p < VCAP) {
            // key: conf descending, orig index ascending == JAX stable argsort(-s)
            vkeys[p] = ((u64)(~__float_as_uint(conf)) << 32) | (u32)i;
            vboxes[p] = c;
        }
    }
}

// Kernel 2: single block. Rank-sort valid keys (canonical order), build
// suppression bit-matrix, single-thread word-serial greedy scan, scatter
// kept entries to output.
__global__ __launch_bounds__(NT) void nms_kernel(
    float* __restrict__ out, const u64* __restrict__ vkeys,
    const float4* __restrict__ vboxes, const int* __restrict__ vcount)
{
    __shared__ u64 tkey[VCAP];          // unsorted keys   (8 KB)
    __shared__ u64 skey[VCAP];          // sorted keys     (8 KB)
    __shared__ float4 sbox[VCAP];       // sorted boxes    (16 KB)
    __shared__ u64 sup[512 * 8];        // suppression bit-matrix (32 KB)
    __shared__ u64 live[8];             // final keep words
    __shared__ unsigned char keepb[VCAP]; // fallback flags (1 KB)

    int tid = threadIdx.x;
    int V = *vcount;
    if (V > VCAP) V = VCAP;
    if (V <= 0) return;

    for (int s = tid; s < V; s += NT) tkey[s] = vkeys[s];
    __syncthreads();

    // rank sort: keys are unique -> rank is a permutation
    for (int s = tid; s < V; s += NT) {
        u64 k = tkey[s];
        int r = 0;
        for (int j = 0; j < V; ++j) r += (tkey[j] < k);
        skey[r] = k;
        sbox[r] = vboxes[s];
    }
    __syncthreads();
    // ascending key == conf descending, index ascending

    if (V <= 512) {
        int nw = (V + 63) >> 6;
        // suppression bit-matrix: sup[i][l] bit (j&63) set iff j>i && iou>thr
        for (int w = tid; w < V * 8; w += NT) {
            int i = w >> 3, l = w & 7;
            u64 bits = 0;
            if (l < nw) {
                float4 bi = sbox[i];
                float ai = fmaxf(bi.z - bi.x, 0.f) * fmaxf(bi.w - bi.y, 0.f);
                int j0 = l << 6;
                int jend = (j0 + 64 < V) ? j0 + 64 : V;
                int js = (j0 > i + 1) ? j0 : i + 1;
                for (int j = js; j < jend; ++j) {
                    float4 bj = sbox[j];
                    float aj = fmaxf(bj.z - bj.x, 0.f) * fmaxf(bj.w - bj.y, 0.f);
                    float ix1 = fmaxf(bi.x, bj.x);
                    float iy1 = fmaxf(bi.y, bj.y);
                    float ix2 = fminf(bi.z, bj.z);
                    float iy2 = fminf(bi.w, bj.w);
                    float inter = fmaxf(ix2 - ix1, 0.f) * fmaxf(iy2 - iy1, 0.f);
                    float iou = inter / (ai + aj - inter + 1e-9f);
                    if (iou > MIN_IOU_F) bits |= 1ull << (j & 63);
                }
            }
            sup[(i << 3) + l] = bits;
        }
        __syncthreads();

        // single-thread word-serial scan. sup rows of word wi only touch
        // j>i, so word wi's final value depends only on its own rows once
        // earlier words' cross-word effects are folded into live[] (done
        // off the critical chain as LDS RMWs).
        if (tid == 0) {
            #pragma unroll
            for (int w = 0; w < 8; ++w) {
                int lo = w << 6;
                u64 m = 0;
                if (lo < V) {
                    int c = V - lo;
                    m = (c >= 64) ? ~0ull : ((1ull << c) - 1ull);
                }
                live[w] = m;
            }
            for (int wi = 0; wi < nw; ++wi) {
                u64 cur = live[wi];
                u64 rem = cur;  // set bits not yet processed and still live
                while (rem) {
                    int b = __ffsll(rem) - 1;
                    rem &= rem - 1;
                    int i = (wi << 6) + b;
                    u64 srow = sup[(i << 3) + wi];
                    cur &= ~srow;       // row has only bits > i (self safe)
                    rem &= cur;
                    for (int w = wi + 1; w < nw; ++w)
                        live[w] &= ~sup[(i << 3) + w];   // off critical chain
                }
                live[wi] = cur;
            }
        }
        __syncthreads();

        for (int s = tid; s < V; s += NT) {
            if ((live[s >> 6] >> (s & 63)) & 1ull) {
                u64 k = skey[s];
                u32 orig = (u32)(k & 0xFFFFFFFFull);
                float conf = __uint_as_float(~(u32)(k >> 32)); // exact roundtrip
                float4 b = sbox[s];
                *reinterpret_cast<float4*>(out + 4 * orig) = b;
                out[4 * M_BOXES + orig] = conf;
                out[6 * M_BOXES + orig] = 1.0f;
            }
        }
    } else {
        // fallback (statistically unreachable): per-i parallel suppression
        for (int s = tid; s < V; s += NT) keepb[s] = 1;
        __syncthreads();
        for (int i = 0; i < V; ++i) {
            if (keepb[i]) {  // uniform read
                float4 bi = sbox[i];
                float ai = fmaxf(bi.z - bi.x, 0.f) * fmaxf(bi.w - bi.y, 0.f);
                for (int s = i + 1 + tid; s < V; s += NT) {
                    if (keepb[s]) {
                        float4 bj = sbox[s];
                        float aj = fmaxf(bj.z - bj.x, 0.f) * fmaxf(bj.w - bj.y, 0.f);
                        float ix1 = fmaxf(bi.x, bj.x);
                        float iy1 = fmaxf(bi.y, bj.y);
                        float ix2 = fminf(bi.z, bj.z);
                        float iy2 = fminf(bi.w, bj.w);
                        float inter = fmaxf(ix2 - ix1, 0.f) * fmaxf(iy2 - iy1, 0.f);
                        float iou = inter / (ai + aj - inter + 1e-9f);
                        if (iou > MIN_IOU_F) keepb[s] = 0;
                    }
                }
            }
            __syncthreads();
        }
        for (int s = tid; s < V; s += NT) {
            if (keepb[s]) {
                u64 k = skey[s];
                u32 orig = (u32)(k & 0xFFFFFFFFull);
                float conf = __uint_as_float(~(u32)(k >> 32));
                float4 b = sbox[s];
                *reinterpret_cast<float4*>(out + 4 * orig) = b;
                out[4 * M_BOXES + orig] = conf;
                out[6 * M_BOXES + orig] = 1.0f;
            }
        }
    }
}

extern "C" void kernel_launch(void* const* d_in, const int* in_sizes, int n_in,
                              void* d_out, int out_size, void* d_ws, size_t ws_size,
                              hipStream_t stream) {
    const float* boxes_raw = (const float*)d_in[0];
    const float* scores    = (const float*)d_in[1];
    const int*   indices   = (const int*)d_in[2];
    const int*   p_out_h   = (const int*)d_in[3];
    const int*   p_out_w   = (const int*)d_in[4];
    float* out = (float*)d_out;

    int*    vcount = (int*)d_ws;
    u64*    vkeys  = (u64*)((char*)d_ws + 16);
    float4* vboxes = (float4*)((char*)d_ws + 16 + VCAP * sizeof(u64));

    hipMemsetAsync(d_ws, 0, 16, stream);
    gather_kernel<<<M_BOXES / 256, 256, 0, stream>>>(
        boxes_raw, scores, indices, p_out_h, p_out_w, out, vkeys, vboxes, vcount);
    nms_kernel<<<1, NT, 0, stream>>>(out, vkeys, vboxes, vcount);
}

// Round 3
// 86.036 us; speedup vs baseline: 1.2688x; 1.2688x over previous
//
#include <hip/hip_runtime.h>
#include <stdint.h>

#define M_BOXES 8192
#define MIN_CONF_F 0.25f
#define MIN_IOU_F 0.45f
#define VCAP 1024
#define NT 1024
#define SUP_STRIDE 9   // u64 words per bit-matrix row (8 + 1 pad -> 4-way banks max)

typedef unsigned long long u64;
typedef unsigned int u32;

__device__ inline float scalar_to_float(const int* p) {
    int v = p[0];
    if (v > 0 && v < (1 << 20)) return (float)v;   // plain int
    return __int_as_float(v);                      // float bit-pattern
}

__device__ inline u64 rl64(u64 v, int b) {
    u32 lo = (u32)__builtin_amdgcn_readlane((int)(u32)v, b);
    u32 hi = (u32)__builtin_amdgcn_readlane((int)(u32)(v >> 32), b);
    return ((u64)hi << 32) | lo;
}

// Kernel 1: gather + validity compaction. Writes ZEROS for boxes/conf/keep
// (kept entries scatter-written by nms_kernel), class for all entries.
__global__ __launch_bounds__(256) void gather_kernel(
    const float* __restrict__ boxes_raw, const float* __restrict__ scores,
    const int* __restrict__ indices, const int* __restrict__ p_out_h,
    const int* __restrict__ p_out_w, float* __restrict__ out,
    u64* __restrict__ vkeys, float4* __restrict__ vboxes,
    int* __restrict__ vcount)
{
    int i = blockIdx.x * blockDim.x + threadIdx.x;
    if (i >= M_BOXES) return;
    int cls = indices[3 * i + 1];
    int idx = indices[3 * i + 2];
    float conf = scores[cls * M_BOXES + idx];
    *reinterpret_cast<float4*>(out + 4 * i) = make_float4(0.f, 0.f, 0.f, 0.f);
    out[4 * M_BOXES + i] = 0.f;
    out[5 * M_BOXES + i] = (float)cls;
    out[6 * M_BOXES + i] = 0.f;
    bool valid = (conf > MIN_CONF_F) &&
                 (cls == 2 || cls == 3 || cls == 5 || cls == 7);
    if (valid) {
        float4 b = *reinterpret_cast<const float4*>(boxes_raw + 4 * idx); // y1,x1,y2,x2
        float W = scalar_to_float(p_out_w);
        float H = scalar_to_float(p_out_h);
        float4 c;
        c.x = fminf(fmaxf(b.y, 0.f), W);   // x1
        c.y = fminf(fmaxf(b.x, 0.f), H);   // y1
        c.z = fminf(fmaxf(b.w, 0.f), W);   // x2
        c.w = fminf(fmaxf(b.z, 0.f), H);   // y2
        int p = atomicAdd(vcount, 1);
        if (p < VCAP) {
            // key: conf descending, orig index ascending == JAX stable argsort(-s)
            vkeys[p] = ((u64)(~__float_as_uint(conf)) << 32) | (u32)i;
            vboxes[p] = c;
        }
    }
}

// Kernel 2: single block. Rank-sort keys (canonical order), wave-ballot
// suppression bit-matrix, single-wave readlane-based greedy scan (register-
// resident serial chain), scatter kept entries.
__global__ __launch_bounds__(NT) void nms_kernel(
    float* __restrict__ out, const u64* __restrict__ vkeys,
    const float4* __restrict__ vboxes, const int* __restrict__ vcount)
{
    __shared__ u64 tkey[VCAP];                 // 8 KB
    __shared__ u64 skey[VCAP];                 // 8 KB
    __shared__ float4 sbox[VCAP];              // 16 KB
    __shared__ u64 sup[512 * SUP_STRIDE];      // 36 KB
    __shared__ u64 live_lds[8];
    __shared__ unsigned char keepb[VCAP];      // fallback only

    int tid = threadIdx.x;
    int V = *vcount;
    if (V > VCAP) V = VCAP;
    if (V <= 0) return;

    for (int s = tid; s < V; s += NT) tkey[s] = vkeys[s];
    __syncthreads();

    // rank sort: keys unique -> rank is a permutation. tkey[j] reads are
    // wave-lockstep broadcasts (conflict-free).
    for (int s = tid; s < V; s += NT) {
        u64 k = tkey[s];
        int r = 0;
        for (int j = 0; j < V; ++j) r += (tkey[j] < k);
        skey[r] = k;
        sbox[r] = vboxes[s];
    }
    __syncthreads();
    // ascending key == conf descending, index ascending

    if (V <= 512) {
        int nw = (V + 63) >> 6;
        int wave = tid >> 6, lane = tid & 63;

        // suppression bit-matrix via per-wave ballot: task t=(i<<3)|w.
        // sup[i][w] bit b set iff j=w*64+b satisfies j>i && j<V && iou>thr.
        int ntask = V << 3;
        for (int t = wave; t < ntask; t += NT / 64) {
            int i = t >> 3, w = t & 7;
            u64 bits = 0;
            if (w < nw) {
                float4 bi = sbox[i];
                float ai = fmaxf(bi.z - bi.x, 0.f) * fmaxf(bi.w - bi.y, 0.f);
                int j = (w << 6) + lane;
                bool p = false;
                if (j > i && j < V) {
                    float4 bj = sbox[j];
                    float aj = fmaxf(bj.z - bj.x, 0.f) * fmaxf(bj.w - bj.y, 0.f);
                    float ix1 = fmaxf(bi.x, bj.x);
                    float iy1 = fmaxf(bi.y, bj.y);
                    float ix2 = fminf(bi.z, bj.z);
                    float iy2 = fminf(bi.w, bj.w);
                    float inter = fmaxf(ix2 - ix1, 0.f) * fmaxf(iy2 - iy1, 0.f);
                    float iou = inter / (ai + aj - inter + 1e-9f);
                    p = iou > MIN_IOU_F;
                }
                bits = __ballot(p);
            }
            if (lane == 0) sup[i * SUP_STRIDE + w] = bits;
        }
        __syncthreads();

        // single-wave scan: chunk ci's rows live in lane VGPRs; serial chain
        // is ffs -> v_readlane -> andn2, all register-resident.
        if (tid < 64) {
            u64 live[8];
            #pragma unroll
            for (int w = 0; w < 8; ++w) {
                int lo = w << 6;
                int c = V - lo;
                live[w] = (c >= 64) ? ~0ull : (c > 0 ? ((1ull << c) - 1ull) : 0ull);
            }
            #pragma unroll
            for (int ci = 0; ci < 8; ++ci) {
                if ((ci << 6) < V) {
                    u64 row[8];
                    int rbase = ((ci << 6) + tid) * SUP_STRIDE;
                    #pragma unroll
                    for (int w = 0; w < 8; ++w) row[w] = sup[rbase + w];
                    u64 cur = live[ci];
                    u64 rem = cur;
                    while (rem) {
                        int b = __builtin_amdgcn_readfirstlane(
                            (int)(__ffsll((long long)rem) - 1));
                        rem &= rem - 1;
                        cur &= ~rl64(row[ci], b);   // row has only bits > i
                        rem &= cur;
                        #pragma unroll
                        for (int w2 = ci + 1; w2 < 8; ++w2)
                            live[w2] &= ~rl64(row[w2], b);  // off critical chain
                    }
                    live[ci] = cur;
                }
            }
            if (tid == 0) {
                #pragma unroll
                for (int w = 0; w < 8; ++w) live_lds[w] = live[w];
            }
        }
        __syncthreads();

        for (int s = tid; s < V; s += NT) {
            if ((live_lds[s >> 6] >> (s & 63)) & 1ull) {
                u64 k = skey[s];
                u32 orig = (u32)(k & 0xFFFFFFFFull);
                float conf = __uint_as_float(~(u32)(k >> 32)); // exact roundtrip
                float4 b = sbox[s];
                *reinterpret_cast<float4*>(out + 4 * orig) = b;
                out[4 * M_BOXES + orig] = conf;
                out[6 * M_BOXES + orig] = 1.0f;
            }
        }
    } else {
        // fallback (statistically unreachable): per-i parallel suppression
        for (int s = tid; s < V; s += NT) keepb[s] = 1;
        __syncthreads();
        for (int i = 0; i < V; ++i) {
            if (keepb[i]) {
                float4 bi = sbox[i];
                float ai = fmaxf(bi.z - bi.x, 0.f) * fmaxf(bi.w - bi.y, 0.f);
                for (int s = i + 1 + tid; s < V; s += NT) {
                    if (keepb[s]) {
                        float4 bj = sbox[s];
                        float aj = fmaxf(bj.z - bj.x, 0.f) * fmaxf(bj.w - bj.y, 0.f);
                        float ix1 = fmaxf(bi.x, bj.x);
                        float iy1 = fmaxf(bi.y, bj.y);
                        float ix2 = fminf(bi.z, bj.z);
                        float iy2 = fminf(bi.w, bj.w);
                        float inter = fmaxf(ix2 - ix1, 0.f) * fmaxf(iy2 - iy1, 0.f);
                        float iou = inter / (ai + aj - inter + 1e-9f);
                        if (iou > MIN_IOU_F) keepb[s] = 0;
                    }
                }
            }
            __syncthreads();
        }
        for (int s = tid; s < V; s += NT) {
            if (keepb[s]) {
                u64 k = skey[s];
                u32 orig = (u32)(k & 0xFFFFFFFFull);
                float conf = __uint_as_float(~(u32)(k >> 32));
                float4 b = sbox[s];
                *reinterpret_cast<float4*>(out + 4 * orig) = b;
                out[4 * M_BOXES + orig] = conf;
                out[6 * M_BOXES + orig] = 1.0f;
            }
        }
    }
}

extern "C" void kernel_launch(void* const* d_in, const int* in_sizes, int n_in,
                              void* d_out, int out_size, void* d_ws, size_t ws_size,
                              hipStream_t stream) {
    const float* boxes_raw = (const float*)d_in[0];
    const float* scores    = (const float*)d_in[1];
    const int*   indices   = (const int*)d_in[2];
    const int*   p_out_h   = (const int*)d_in[3];
    const int*   p_out_w   = (const int*)d_in[4];
    float* out = (float*)d_out;

    int*    vcount = (int*)d_ws;
    u64*    vkeys  = (u64*)((char*)d_ws + 16);
    float4* vboxes = (float4*)((char*)d_ws + 16 + VCAP * sizeof(u64));

    hipMemsetAsync(d_ws, 0, 16, stream);
    gather_kernel<<<M_BOXES / 256, 256, 0, stream>>>(
        boxes_raw, scores, indices, p_out_h, p_out_w, out, vkeys, vboxes, vcount);
    nms_kernel<<<1, NT, 0, stream>>>(out, vkeys, vboxes, vcount);
}

// Round 4
// 75.310 us; speedup vs baseline: 1.4495x; 1.1424x over previous
//
#include <hip/hip_runtime.h>
#include <stdint.h>

#define M_BOXES 8192
#define MIN_CONF_F 0.25f
#define MIN_IOU_F 0.45f
#define VCAP 1024
#define NT 1024
#define NWAVES (NT / 64)
#define SUP_STRIDE 9   // u64 words per bit-matrix row (8 + 1 pad)

typedef unsigned long long u64;
typedef unsigned int u32;

__device__ inline float scalar_to_float(const int* p) {
    int v = p[0];
    if (v > 0 && v < (1 << 20)) return (float)v;   // plain int
    return __int_as_float(v);                      // float bit-pattern
}

__device__ inline u64 rl64(u64 v, int b) {
    u32 lo = (u32)__builtin_amdgcn_readlane((int)(u32)v, b);
    u32 hi = (u32)__builtin_amdgcn_readlane((int)(u32)(v >> 32), b);
    return ((u64)hi << 32) | lo;
}

// Kernel 1: gather + validity. Writes zeros for boxes/conf/keep, class for
// all. mode=1: sentinel-keyed full array (no atomics, no memset needed).
// mode=0: atomic compaction (needs vcount pre-zeroed).
__global__ __launch_bounds__(256) void gather_kernel(
    const float* __restrict__ boxes_raw, const float* __restrict__ scores,
    const int* __restrict__ indices, const int* __restrict__ p_out_h,
    const int* __restrict__ p_out_w, float* __restrict__ out,
    u64* __restrict__ vkeys, float4* __restrict__ vboxes,
    int* __restrict__ vcount, int mode)
{
    int i = blockIdx.x * blockDim.x + threadIdx.x;
    if (i >= M_BOXES) return;
    int cls = indices[3 * i + 1];
    int idx = indices[3 * i + 2];
    float conf = scores[cls * M_BOXES + idx];
    *reinterpret_cast<float4*>(out + 4 * i) = make_float4(0.f, 0.f, 0.f, 0.f);
    out[4 * M_BOXES + i] = 0.f;
    out[5 * M_BOXES + i] = (float)cls;
    out[6 * M_BOXES + i] = 0.f;
    bool valid = (conf > MIN_CONF_F) &&
                 (cls == 2 || cls == 3 || cls == 5 || cls == 7);
    // key: conf descending, orig index ascending == JAX stable argsort(-s)
    u64 key = ((u64)(~__float_as_uint(conf)) << 32) | (u32)i;
    float4 c = make_float4(0.f, 0.f, 0.f, 0.f);
    if (valid) {
        float4 b = *reinterpret_cast<const float4*>(boxes_raw + 4 * idx); // y1,x1,y2,x2
        float W = scalar_to_float(p_out_w);
        float H = scalar_to_float(p_out_h);
        c.x = fminf(fmaxf(b.y, 0.f), W);   // x1
        c.y = fminf(fmaxf(b.x, 0.f), H);   // y1
        c.z = fminf(fmaxf(b.w, 0.f), W);   // x2
        c.w = fminf(fmaxf(b.z, 0.f), H);   // y2
    }
    if (mode) {
        vkeys[i] = valid ? key : ~0ull;
        if (valid) vboxes[i] = c;
    } else if (valid) {
        int p = atomicAdd(vcount, 1);
        if (p < VCAP) { vkeys[p] = key; vboxes[p] = c; }
    }
}

// Kernel 2: single block. Compact (mode=1), rank-sort, triangular tiled
// ballot bit-matrix, register-resident readlane scan, scatter kept entries.
__global__ __launch_bounds__(NT) void nms_kernel(
    float* __restrict__ out, const u64* __restrict__ vkeys,
    const float4* __restrict__ vboxes, const int* __restrict__ vcount,
    int mode)
{
    __shared__ u64 tkey[VCAP];                 // 8 KB unsorted keys
    __shared__ float4 tbox[VCAP];              // 16 KB unsorted boxes
    __shared__ u64 skey[VCAP];                 // 8 KB sorted keys
    __shared__ float4 sbox[VCAP];              // 16 KB sorted boxes
    __shared__ float sarea[VCAP];              // 4 KB sorted areas
    __shared__ u64 sup[512 * SUP_STRIDE];      // 36 KB suppression bits
    __shared__ u64 live_lds[8];
    __shared__ int lcount;
    __shared__ unsigned char keepb[VCAP];      // fallback only

    int tid = threadIdx.x;
    int V;
    if (mode) {
        if (tid == 0) lcount = 0;
        __syncthreads();
        for (int s = tid; s < M_BOXES; s += NT) {
            u64 k = vkeys[s];
            if (k != ~0ull) {
                int p = atomicAdd(&lcount, 1);
                if (p < VCAP) { tkey[p] = k; tbox[p] = vboxes[s]; }
            }
        }
        __syncthreads();
        V = lcount;
        if (V > VCAP) V = VCAP;
    } else {
        V = *vcount;
        if (V > VCAP) V = VCAP;
        for (int s = tid; s < V; s += NT) { tkey[s] = vkeys[s]; tbox[s] = vboxes[s]; }
        __syncthreads();
    }
    if (V <= 0) return;

    // rank sort: unique keys -> rank is a permutation (lockstep broadcasts)
    for (int s = tid; s < V; s += NT) {
        u64 k = tkey[s];
        int r = 0;
        #pragma unroll 4
        for (int j = 0; j < V; ++j) r += (tkey[j] < k);
        skey[r] = k;
        float4 b = tbox[s];
        sbox[r] = b;
        sarea[r] = fmaxf(b.z - b.x, 0.f) * fmaxf(b.w - b.y, 0.f);
    }
    __syncthreads();
    // ascending key == conf descending, index ascending

    if (V <= 512) {
        int nw = (V + 63) >> 6;
        int wave = tid >> 6, lane = tid & 63;

        // triangular tiled matrix: task = (8-row i-block, j-word w).
        // per-lane bj/aj loaded once, reused across 8 rows.
        int nbi = (V + 7) >> 3;
        int ntask = nbi * nw;
        for (int t = wave; t < ntask; t += NWAVES) {
            int bi = t / nw;            // wave-uniform
            int w = t - bi * nw;
            int i0 = bi << 3;
            if (w < (i0 >> 6)) continue;   // fully below diagonal
            int j = (w << 6) + lane;
            bool jv = (j < V);
            float4 bj = jv ? sbox[j] : make_float4(0.f, 0.f, 0.f, 0.f);
            float aj = jv ? sarea[j] : 0.f;
            int rend = V - i0; if (rend > 8) rend = 8;
            for (int r = 0; r < rend; ++r) {
                int i = i0 + r;
                float4 bi_ = sbox[i];      // broadcast
                float ai = sarea[i];       // broadcast
                bool p = false;
                if (jv && j > i) {
                    float ix1 = fmaxf(bi_.x, bj.x);
                    float iy1 = fmaxf(bi_.y, bj.y);
                    float ix2 = fminf(bi_.z, bj.z);
                    float iy2 = fminf(bi_.w, bj.w);
                    float inter = fmaxf(ix2 - ix1, 0.f) * fmaxf(iy2 - iy1, 0.f);
                    float iou = inter / (ai + aj - inter + 1e-9f);
                    p = iou > MIN_IOU_F;
                }
                u64 bits = __ballot(p);
                if (lane == 0) sup[i * SUP_STRIDE + w] = bits;
            }
        }
        __syncthreads();

        // single-wave scan: chunk ci's rows in lane VGPRs; serial chain is
        // ffs -> v_readlane -> andn2. Cross-word updates guarded by nw
        // (wave-uniform scalar branches, static register indices).
        if (tid < 64) {
            u64 live[8];
            #pragma unroll
            for (int w = 0; w < 8; ++w) {
                int c = V - (w << 6);
                live[w] = (c >= 64) ? ~0ull : (c > 0 ? ((1ull << c) - 1ull) : 0ull);
            }
            #pragma unroll
            for (int ci = 0; ci < 8; ++ci) {
                if ((ci << 6) < V) {
                    u64 row[8];
                    int rbase = ((ci << 6) + tid) * SUP_STRIDE;
                    #pragma unroll
                    for (int w = 0; w < 8; ++w)
                        row[w] = (w < nw) ? sup[rbase + w] : 0ull;
                    u64 cur = live[ci];
                    u64 rem = cur;
                    while (rem) {
                        int b = __builtin_amdgcn_readfirstlane(
                            (int)(__ffsll((long long)rem) - 1));
                        rem &= rem - 1;
                        cur &= ~rl64(row[ci], b);   // row has only bits > i
                        rem &= cur;
                        #pragma unroll
                        for (int w2 = 1; w2 < 8; ++w2)
                            if (w2 > ci && w2 < nw)
                                live[w2] &= ~rl64(row[w2], b);  // off chain
                    }
                    live[ci] = cur;
                }
            }
            if (tid == 0) {
                #pragma unroll
                for (int w = 0; w < 8; ++w) live_lds[w] = live[w];
            }
        }
        __syncthreads();

        for (int s = tid; s < V; s += NT) {
            if ((live_lds[s >> 6] >> (s & 63)) & 1ull) {
                u64 k = skey[s];
                u32 orig = (u32)(k & 0xFFFFFFFFull);
                float conf = __uint_as_float(~(u32)(k >> 32)); // exact roundtrip
                float4 b = sbox[s];
                *reinterpret_cast<float4*>(out + 4 * orig) = b;
                out[4 * M_BOXES + orig] = conf;
                out[6 * M_BOXES + orig] = 1.0f;
            }
        }
    } else {
        // fallback (statistically unreachable): per-i parallel suppression
        for (int s = tid; s < V; s += NT) keepb[s] = 1;
        __syncthreads();
        for (int i = 0; i < V; ++i) {
            if (keepb[i]) {
                float4 bi = sbox[i];
                float ai = fmaxf(bi.z - bi.x, 0.f) * fmaxf(bi.w - bi.y, 0.f);
                for (int s = i + 1 + tid; s < V; s += NT) {
                    if (keepb[s]) {
                        float4 bj = sbox[s];
                        float aj = fmaxf(bj.z - bj.x, 0.f) * fmaxf(bj.w - bj.y, 0.f);
                        float ix1 = fmaxf(bi.x, bj.x);
                        float iy1 = fmaxf(bi.y, bj.y);
                        float ix2 = fminf(bi.z, bj.z);
                        float iy2 = fminf(bi.w, bj.w);
                        float inter = fmaxf(ix2 - ix1, 0.f) * fmaxf(iy2 - iy1, 0.f);
                        float iou = inter / (ai + aj - inter + 1e-9f);
                        if (iou > MIN_IOU_F) keepb[s] = 0;
                    }
                }
            }
            __syncthreads();
        }
        for (int s = tid; s < V; s += NT) {
            if (keepb[s]) {
                u64 k = skey[s];
                u32 orig = (u32)(k & 0xFFFFFFFFull);
                float conf = __uint_as_float(~(u32)(k >> 32));
                float4 b = sbox[s];
                *reinterpret_cast<float4*>(out + 4 * orig) = b;
                out[4 * M_BOXES + orig] = conf;
                out[6 * M_BOXES + orig] = 1.0f;
            }
        }
    }
}

extern "C" void kernel_launch(void* const* d_in, const int* in_sizes, int n_in,
                              void* d_out, int out_size, void* d_ws, size_t ws_size,
                              hipStream_t stream) {
    const float* boxes_raw = (const float*)d_in[0];
    const float* scores    = (const float*)d_in[1];
    const int*   indices   = (const int*)d_in[2];
    const int*   p_out_h   = (const int*)d_in[3];
    const int*   p_out_w   = (const int*)d_in[4];
    float* out = (float*)d_out;

    size_t need = (size_t)M_BOXES * 8 + (size_t)M_BOXES * 16;  // 196608 B
    if (ws_size >= need) {
        // mode 1: sentinel keys, no memset, no atomics in gather
        u64*    vkeys  = (u64*)d_ws;
        float4* vboxes = (float4*)((char*)d_ws + (size_t)M_BOXES * 8);
        gather_kernel<<<M_BOXES / 256, 256, 0, stream>>>(
            boxes_raw, scores, indices, p_out_h, p_out_w, out,
            vkeys, vboxes, nullptr, 1);
        nms_kernel<<<1, NT, 0, stream>>>(out, vkeys, vboxes, nullptr, 1);
    } else {
        // mode 0 fallback: atomic compaction, small workspace
        int*    vcount = (int*)d_ws;
        u64*    vkeys  = (u64*)((char*)d_ws + 16);
        float4* vboxes = (float4*)((char*)d_ws + 16 + VCAP * sizeof(u64));
        hipMemsetAsync(d_ws, 0, 16, stream);
        gather_kernel<<<M_BOXES / 256, 256, 0, stream>>>(
            boxes_raw, scores, indices, p_out_h, p_out_w, out,
            vkeys, vboxes, vcount, 0);
        nms_kernel<<<1, NT, 0, stream>>>(out, vkeys, vboxes, vcount, 0);
    }
}

// Round 5
// 50.872 us; speedup vs baseline: 2.1459x; 1.4804x over previous
//
#include <hip/hip_runtime.h>
#include <stdint.h>

#define M_BOXES 8192
#define MIN_CONF_F 0.25f
#define MIN_IOU_F 0.45f
#define VCAP 1024
#define NT 1024
#define NWAVES (NT / 64)
#define SUP_STRIDE 9   // u64 words per bit-matrix row (8 + 1 pad)

typedef unsigned long long u64;
typedef unsigned int u32;

__device__ inline float scalar_to_float(const int* p) {
    int v = p[0];
    if (v > 0 && v < (1 << 20)) return (float)v;   // plain int
    return __int_as_float(v);                      // float bit-pattern
}

__device__ inline u64 rl64(u64 v, int b) {
    u32 lo = (u32)__builtin_amdgcn_readlane((int)(u32)v, b);
    u32 hi = (u32)__builtin_amdgcn_readlane((int)(u32)(v >> 32), b);
    return ((u64)hi << 32) | lo;
}

__device__ inline u64 wave_or64(u64 v) {
    #pragma unroll
    for (int o = 32; o > 0; o >>= 1) {
        int lo = __shfl_xor((int)(u32)v, o, 64);
        int hi = __shfl_xor((int)(u32)(v >> 32), o, 64);
        v |= ((u64)(u32)hi << 32) | (u32)lo;
    }
    return v;
}

// Kernel 1: gather + validity. Writes zeros for boxes/conf/keep, class for
// all. mode=1: sentinel-keyed full array (no atomics, no memset needed).
__global__ __launch_bounds__(256) void gather_kernel(
    const float* __restrict__ boxes_raw, const float* __restrict__ scores,
    const int* __restrict__ indices, const int* __restrict__ p_out_h,
    const int* __restrict__ p_out_w, float* __restrict__ out,
    u64* __restrict__ vkeys, float4* __restrict__ vboxes,
    int* __restrict__ vcount, int mode)
{
    int i = blockIdx.x * blockDim.x + threadIdx.x;
    if (i >= M_BOXES) return;
    int cls = indices[3 * i + 1];
    int idx = indices[3 * i + 2];
    float conf = scores[cls * M_BOXES + idx];
    *reinterpret_cast<float4*>(out + 4 * i) = make_float4(0.f, 0.f, 0.f, 0.f);
    out[4 * M_BOXES + i] = 0.f;
    out[5 * M_BOXES + i] = (float)cls;
    out[6 * M_BOXES + i] = 0.f;
    bool valid = (conf > MIN_CONF_F) &&
                 (cls == 2 || cls == 3 || cls == 5 || cls == 7);
    // key: conf descending, orig index ascending == JAX stable argsort(-s)
    u64 key = ((u64)(~__float_as_uint(conf)) << 32) | (u32)i;
    float4 c = make_float4(0.f, 0.f, 0.f, 0.f);
    if (valid) {
        float4 b = *reinterpret_cast<const float4*>(boxes_raw + 4 * idx); // y1,x1,y2,x2
        float W = scalar_to_float(p_out_w);
        float H = scalar_to_float(p_out_h);
        c.x = fminf(fmaxf(b.y, 0.f), W);   // x1
        c.y = fminf(fmaxf(b.x, 0.f), H);   // y1
        c.z = fminf(fmaxf(b.w, 0.f), W);   // x2
        c.w = fminf(fmaxf(b.z, 0.f), H);   // y2
    }
    if (mode) {
        vkeys[i] = valid ? key : ~0ull;
        if (valid) vboxes[i] = c;
    } else if (valid) {
        int p = atomicAdd(vcount, 1);
        if (p < VCAP) { vkeys[p] = key; vboxes[p] = c; }
    }
}

// Kernel 2: single block. Compact, rank-sort, triangular tiled ballot
// bit-matrix, branch-free single-wave scan, scatter kept entries.
__global__ __launch_bounds__(NT) void nms_kernel(
    float* __restrict__ out, const u64* __restrict__ vkeys,
    const float4* __restrict__ vboxes, const int* __restrict__ vcount,
    int mode)
{
    __shared__ u64 tkey[VCAP];                 // 8 KB unsorted keys
    __shared__ float4 tbox[VCAP];              // 16 KB unsorted boxes
    __shared__ u64 skey[VCAP];                 // 8 KB sorted keys
    __shared__ float4 sbox[VCAP];              // 16 KB sorted boxes
    __shared__ float sarea[VCAP];              // 4 KB sorted areas
    __shared__ u64 sup[512 * SUP_STRIDE];      // 36 KB suppression bits
    __shared__ u64 supp_lds[8];                // suppressed-bit accumulator
    __shared__ u64 live_lds[8];                // final keep words
    __shared__ int lcount;
    __shared__ unsigned char keepb[VCAP];      // fallback only

    int tid = threadIdx.x;
    int V;
    if (mode) {
        if (tid == 0) lcount = 0;
        __syncthreads();
        for (int s = tid; s < M_BOXES; s += NT) {
            u64 k = vkeys[s];
            if (k != ~0ull) {
                int p = atomicAdd(&lcount, 1);
                if (p < VCAP) { tkey[p] = k; tbox[p] = vboxes[s]; }
            }
        }
        __syncthreads();
        V = lcount;
        if (V > VCAP) V = VCAP;
    } else {
        V = *vcount;
        if (V > VCAP) V = VCAP;
        for (int s = tid; s < V; s += NT) { tkey[s] = vkeys[s]; tbox[s] = vboxes[s]; }
        __syncthreads();
    }
    if (V <= 0) return;

    // rank sort: unique keys -> rank is a permutation (lockstep broadcasts)
    for (int s = tid; s < V; s += NT) {
        u64 k = tkey[s];
        int r = 0;
        #pragma unroll 4
        for (int j = 0; j < V; ++j) r += (tkey[j] < k);
        skey[r] = k;
        float4 b = tbox[s];
        sbox[r] = b;
        sarea[r] = fmaxf(b.z - b.x, 0.f) * fmaxf(b.w - b.y, 0.f);
    }
    __syncthreads();
    // ascending key == conf descending, index ascending

    if (V <= 512) {
        int nw = (V + 63) >> 6;
        int wave = tid >> 6, lane = tid & 63;

        // triangular tiled matrix: task = (8-row i-block, j-word w).
        int nbi = (V + 7) >> 3;
        int ntask = nbi * nw;
        for (int t = wave; t < ntask; t += NWAVES) {
            int bi = t / nw;            // wave-uniform
            int w = t - bi * nw;
            int i0 = bi << 3;
            if (w < (i0 >> 6)) continue;   // fully below diagonal
            int j = (w << 6) + lane;
            bool jv = (j < V);
            float4 bj = jv ? sbox[j] : make_float4(0.f, 0.f, 0.f, 0.f);
            float aj = jv ? sarea[j] : 0.f;
            int rend = V - i0; if (rend > 8) rend = 8;
            for (int r = 0; r < rend; ++r) {
                int i = i0 + r;
                float4 bi_ = sbox[i];      // broadcast
                float ai = sarea[i];       // broadcast
                bool p = false;
                if (jv && j > i) {
                    float ix1 = fmaxf(bi_.x, bj.x);
                    float iy1 = fmaxf(bi_.y, bj.y);
                    float ix2 = fminf(bi_.z, bj.z);
                    float iy2 = fminf(bi_.w, bj.w);
                    float inter = fmaxf(ix2 - ix1, 0.f) * fmaxf(iy2 - iy1, 0.f);
                    float iou = inter / (ai + aj - inter + 1e-9f);
                    p = iou > MIN_IOU_F;
                }
                u64 bits = __ballot(p);
                if (lane == 0) sup[i * SUP_STRIDE + w] = bits;
            }
        }
        __syncthreads();

        // single-wave branch-free scan. Word ci resolved by a 64-step
        // branchless recurrence (readlane with compile-time lane index);
        // cross-word suppression applied once per word via wave OR-reduce.
        if (tid < 64) {
            int lane = tid;
            if (lane < 8) { supp_lds[lane] = 0ull; live_lds[lane] = 0ull; }
            __asm__ volatile("s_waitcnt lgkmcnt(0)" ::: "memory");

            for (int ci = 0; ci < nw; ++ci) {       // wave-uniform runtime loop
                int rowbase = ((ci << 6) + lane) * SUP_STRIDE;
                u64 rw = sup[rowbase + ci];         // lane's row, word ci
                int c = V - (ci << 6);
                u64 init = (c >= 64) ? ~0ull : ((1ull << c) - 1ull);
                u64 cur = init & ~supp_lds[ci];
                #pragma unroll
                for (int b = 0; b < 64; ++b) {
                    u64 rb = rl64(rw, b);           // imm lane index
                    u64 nxt = cur & ~rb;            // row only has bits > b
                    cur = ((cur >> b) & 1ull) ? nxt : cur;
                }
                if (lane == 0) live_lds[ci] = cur;
                for (int w2 = ci + 1; w2 < nw; ++w2) {   // wave-uniform
                    u64 mine = ((cur >> lane) & 1ull) ? sup[rowbase + w2] : 0ull;
                    mine = wave_or64(mine);
                    if (lane == 0) supp_lds[w2] |= mine;
                }
                __asm__ volatile("s_waitcnt lgkmcnt(0)" ::: "memory");
            }
        }
        __syncthreads();

        for (int s = tid; s < V; s += NT) {
            if ((live_lds[s >> 6] >> (s & 63)) & 1ull) {
                u64 k = skey[s];
                u32 orig = (u32)(k & 0xFFFFFFFFull);
                float conf = __uint_as_float(~(u32)(k >> 32)); // exact roundtrip
                float4 b = sbox[s];
                *reinterpret_cast<float4*>(out + 4 * orig) = b;
                out[4 * M_BOXES + orig] = conf;
                out[6 * M_BOXES + orig] = 1.0f;
            }
        }
    } else {
        // fallback (statistically unreachable): per-i parallel suppression
        for (int s = tid; s < V; s += NT) keepb[s] = 1;
        __syncthreads();
        for (int i = 0; i < V; ++i) {
            if (keepb[i]) {
                float4 bi = sbox[i];
                float ai = fmaxf(bi.z - bi.x, 0.f) * fmaxf(bi.w - bi.y, 0.f);
                for (int s = i + 1 + tid; s < V; s += NT) {
                    if (keepb[s]) {
                        float4 bj = sbox[s];
                        float aj = fmaxf(bj.z - bj.x, 0.f) * fmaxf(bj.w - bj.y, 0.f);
                        float ix1 = fmaxf(bi.x, bj.x);
                        float iy1 = fmaxf(bi.y, bj.y);
                        float ix2 = fminf(bi.z, bj.z);
                        float iy2 = fminf(bi.w, bj.w);
                        float inter = fmaxf(ix2 - ix1, 0.f) * fmaxf(iy2 - iy1, 0.f);
                        float iou = inter / (ai + aj - inter + 1e-9f);
                        if (iou > MIN_IOU_F) keepb[s] = 0;
                    }
                }
            }
            __syncthreads();
        }
        for (int s = tid; s < V; s += NT) {
            if (keepb[s]) {
                u64 k = skey[s];
                u32 orig = (u32)(k & 0xFFFFFFFFull);
                float conf = __uint_as_float(~(u32)(k >> 32));
                float4 b = sbox[s];
                *reinterpret_cast<float4*>(out + 4 * orig) = b;
                out[4 * M_BOXES + orig] = conf;
                out[6 * M_BOXES + orig] = 1.0f;
            }
        }
    }
}

extern "C" void kernel_launch(void* const* d_in, const int* in_sizes, int n_in,
                              void* d_out, int out_size, void* d_ws, size_t ws_size,
                              hipStream_t stream) {
    const float* boxes_raw = (const float*)d_in[0];
    const float* scores    = (const float*)d_in[1];
    const int*   indices   = (const int*)d_in[2];
    const int*   p_out_h   = (const int*)d_in[3];
    const int*   p_out_w   = (const int*)d_in[4];
    float* out = (float*)d_out;

    size_t need = (size_t)M_BOXES * 8 + (size_t)M_BOXES * 16;  // 196608 B
    if (ws_size >= need) {
        u64*    vkeys  = (u64*)d_ws;
        float4* vboxes = (float4*)((char*)d_ws + (size_t)M_BOXES * 8);
        gather_kernel<<<M_BOXES / 256, 256, 0, stream>>>(
            boxes_raw, scores, indices, p_out_h, p_out_w, out,
            vkeys, vboxes, nullptr, 1);
        nms_kernel<<<1, NT, 0, stream>>>(out, vkeys, vboxes, nullptr, 1);
    } else {
        int*    vcount = (int*)d_ws;
        u64*    vkeys  = (u64*)((char*)d_ws + 16);
        float4* vboxes = (float4*)((char*)d_ws + 16 + VCAP * sizeof(u64));
        hipMemsetAsync(d_ws, 0, 16, stream);
        gather_kernel<<<M_BOXES / 256, 256, 0, stream>>>(
            boxes_raw, scores, indices, p_out_h, p_out_w, out,
            vkeys, vboxes, vcount, 0);
        nms_kernel<<<1, NT, 0, stream>>>(out, vkeys, vboxes, vcount, 0);
    }
}